// Round 7
// baseline (369.219 us; speedup 1.0000x reference)
//
#include <hip/hip_runtime.h>
#include <hip/hip_bf16.h>

// Problem: B=8192, D_IN=1024, D_OUT=1024, E=16
#define NB 8192
#define DIN 1024
#define DOUT 1024
#define NE 16

// GEMM tile geometry: split-K=2 (8 experts per block), BM=BN=256, BK=64
#define BM 256
#define BN 256
#define BK 64
#define NT 128  // (8 experts * 1024) / 64

typedef __attribute__((ext_vector_type(8))) short bf16x8;
typedef __attribute__((ext_vector_type(4))) short short4_t;
typedef __attribute__((ext_vector_type(4))) float f32x4;
typedef __attribute__((ext_vector_type(16))) float f32x16;

__device__ __forceinline__ unsigned short f32_to_bf16(float f) {
  unsigned int u = __float_as_uint(f);
  u += 0x7FFFu + ((u >> 16) & 1u);  // RNE
  return (unsigned short)(u >> 16);
}

__device__ __forceinline__ void gl_lds16(const void* gp, void* lp) {
  __builtin_amdgcn_global_load_lds(
      (const __attribute__((address_space(1))) void*)gp,
      (__attribute__((address_space(3))) void*)lp, 16, 0, 0);
}

#define SB __builtin_amdgcn_sched_barrier(0)

// ---------------- Kernel 1: gate softmax (f32) + x -> bf16 cast --------------
__global__ __launch_bounds__(256) void gate_cast_kernel(
    const float* __restrict__ x, const float* __restrict__ Wg,
    const float* __restrict__ bg, float* __restrict__ gout,
    unsigned short* __restrict__ xbf) {
  const int lane = threadIdx.x & 63;
  const int wid = threadIdx.x >> 6;
  const int row = blockIdx.x * 4 + wid;

  const f32x4* xr = (const f32x4*)(x + (size_t)row * DIN);
  f32x4 xv[4];
#pragma unroll
  for (int j = 0; j < 4; ++j) xv[j] = xr[j * 64 + lane];

  float acc[NE];
#pragma unroll
  for (int e = 0; e < NE; ++e) acc[e] = 0.f;

#pragma unroll
  for (int j = 0; j < 4; ++j) {
#pragma unroll
    for (int t = 0; t < 4; ++t) {
      const int i = j * 256 + lane * 4 + t;
      const f32x4* wrow = (const f32x4*)(Wg + (size_t)i * NE);
      const f32x4 w0 = wrow[0], w1 = wrow[1], w2 = wrow[2], w3 = wrow[3];
      const float xx = xv[j][t];
#pragma unroll
      for (int q = 0; q < 4; ++q) {
        acc[q]      = fmaf(xx, w0[q], acc[q]);
        acc[4 + q]  = fmaf(xx, w1[q], acc[4 + q]);
        acc[8 + q]  = fmaf(xx, w2[q], acc[8 + q]);
        acc[12 + q] = fmaf(xx, w3[q], acc[12 + q]);
      }
    }
  }
#pragma unroll
  for (int off = 32; off >= 1; off >>= 1) {
#pragma unroll
    for (int e = 0; e < NE; ++e) acc[e] += __shfl_xor(acc[e], off, 64);
  }
#pragma unroll
  for (int e = 0; e < NE; ++e) acc[e] += bg[e];
  float mx = acc[0];
#pragma unroll
  for (int e = 1; e < NE; ++e) mx = fmaxf(mx, acc[e]);
  float p[NE];
  float s = 0.f;
#pragma unroll
  for (int e = 0; e < NE; ++e) { p[e] = expf(acc[e] - mx); s += p[e]; }
  const float inv = 1.f / s;
  if (lane == 0) {
#pragma unroll
    for (int e = 0; e < NE; ++e) gout[(size_t)row * NE + e] = p[e] * inv;
  }
#pragma unroll
  for (int j = 0; j < 4; ++j) {
    short4_t o;
#pragma unroll
    for (int t = 0; t < 4; ++t) o[t] = (short)f32_to_bf16(xv[j][t]);
    *(short4_t*)(xbf + (size_t)row * DIN + j * 256 + lane * 4) = o;
  }
}

// ------------- Kernel 2: We[e,i,o] f32 -> WeT[e,o,i] bf16 (transpose) --------
__global__ __launch_bounds__(256) void we_transpose_kernel(
    const float* __restrict__ We, unsigned short* __restrict__ WeT) {
  __shared__ float tile[64][65];
  const int e = blockIdx.z, it = blockIdx.y, ot = blockIdx.x;
  const int tr = threadIdx.x >> 4;
  const int tc = (threadIdx.x & 15) * 4;
  const float* src = We + (((size_t)e * DIN + it * 64) * DOUT) + ot * 64;
#pragma unroll
  for (int rr = 0; rr < 64; rr += 16) {
    const f32x4 v = *(const f32x4*)(src + (size_t)(rr + tr) * DOUT + tc);
#pragma unroll
    for (int t = 0; t < 4; ++t) tile[rr + tr][tc + t] = v[t];
  }
  __syncthreads();
  unsigned short* dst = WeT + (((size_t)e * DOUT + ot * 64) * DIN) + it * 64;
#pragma unroll
  for (int rr = 0; rr < 64; rr += 16) {
    short4_t o;
#pragma unroll
    for (int t = 0; t < 4; ++t) o[t] = (short)f32_to_bf16(tile[tc + t][rr + tr]);
    *(short4_t*)(dst + (size_t)(rr + tr) * DIN + tc) = o;
  }
}

// ------------- Kernel 3: split-K MoE GEMM, 32x32x16, 1 barrier/tile ----------
// 8 waves 2Mx4N, per-wave 128x64 = 4mi x 2ni frags of 32x32, 4 ks of K=16.
// Free-running waves inside a tile; sync points per tile:
//   mid: vmcnt(6) (drains own Ah1, leaves 6 chunks of t+1)
//   boundary: vmcnt(2) (drains t+1's B+Ah0, leaves Ah1) + s_barrier
__global__ __launch_bounds__(512, 2) void moe_gemm_kernel(
    const unsigned short* __restrict__ xbf,   // [8192][1024] bf16
    const unsigned short* __restrict__ WeT,   // [16][1024 o][1024 i] bf16
    const float* __restrict__ g,              // [8192][16]
    const float* __restrict__ be,             // [16][1024]
    float* __restrict__ out0,                 // kh=0 -> d_out
    float* __restrict__ out1) {               // kh=1 -> partial ws
  __shared__ __align__(16) unsigned short As[2][BM * BK];  // 2x32 KiB
  __shared__ __align__(16) unsigned short Bs[2][BN * BK];  // 2x32 KiB
  __shared__ float gs[BM][NE];                             // 16 KiB

  const int tid = threadIdx.x;
  const int lane = tid & 63, wid = tid >> 6;
  const int wm = wid >> 2, wn = wid & 3;
  const int l31 = lane & 31, lh = lane >> 5;

  const int bid = blockIdx.x;
  const int xcd = bid & 7, jj_ = bid >> 3;
  const int kh = xcd >> 2;
  const int brow = ((xcd & 3) * 8 + (jj_ >> 2)) * BM;
  const int bcol = (jj_ & 3) * BN;
  float* const outp = kh ? out1 : out0;

  // LDS read bases; swizzle term depends only on lane (rows step by 32)
  const int swz = (l31 & 7) << 4;
  int offK[4];
#pragma unroll
  for (int ks = 0; ks < 4; ++ks) offK[ks] = ((ks << 5) | (lh << 4)) ^ swz;
  const char* const ldsA = (const char*)&As[0][0] + (wm * 128 + l31) * 128;
  const char* const ldsB = (const char*)&Bs[0][0] + (wn * 64 + l31) * 128;

  // staging (T2 both-sides: linear LDS dst, inverse-swizzled global src)
  const int srow = tid >> 3;
  const int lk = (((tid & 7) * 16) ^ ((srow & 7) << 4)) >> 1;
  const unsigned short* const aBase = xbf + (size_t)(brow + srow) * DIN + lk;
  const unsigned short* const bBase = WeT + (size_t)(bcol + srow) * DIN + lk;
  char* const ldsStA = (char*)&As[0][0] + wid * 1024;  // wave-uniform
  char* const ldsStB = (char*)&Bs[0][0] + wid * 1024;

#define STA(BUF, CR, KC) \
  gl_lds16(aBase + (size_t)(CR) * DIN + (KC), \
           ldsStA + (BUF) * 32768 + (CR) * 128)
#define STB(BUF, CR, EOFF, KC) \
  gl_lds16(bBase + (EOFF) + (size_t)(CR) * DIN + (KC), \
           ldsStB + (BUF) * 32768 + (CR) * 128)
#define RD_B(BUF)                                                   \
  _Pragma("unroll") for (int ni = 0; ni < 2; ++ni)                  \
  _Pragma("unroll") for (int ks = 0; ks < 4; ++ks)                  \
      bfr[ni][ks] = *(const bf16x8*)(ldsB + (BUF) * 32768 +         \
                                     ni * 4096 + offK[ks]);
#define RD_A(MI, SLOT, BUF)                                         \
  _Pragma("unroll") for (int ks = 0; ks < 4; ++ks)                  \
      afr[SLOT][ks] = *(const bf16x8*)(ldsA + (BUF) * 32768 +       \
                                       (MI) * 4096 + offK[ks]);
#define MFMA8(MI, SLOT)                                             \
  _Pragma("unroll") for (int ks = 0; ks < 4; ++ks)                  \
  _Pragma("unroll") for (int ni = 0; ni < 2; ++ni)                  \
      acc[MI][ni] = __builtin_amdgcn_mfma_f32_32x32x16_bf16(        \
          afr[SLOT][ks], bfr[ni][ks], acc[MI][ni], 0, 0, 0);

  {  // gate tile -> LDS
    const f32x4* gsrc = (const f32x4*)(g + (size_t)brow * NE);
    f32x4* gdst = (f32x4*)&gs[0][0];
    gdst[tid] = gsrc[tid];
    gdst[tid + 512] = gsrc[tid + 512];
  }

  // prologue: B(0) 4 chunks + Ah0(0), then Ah1(0)
  {
    const size_t e0 = (size_t)(kh * 8) * (size_t)(DIN * DOUT);
    STB(0, 0, e0, 0); STB(0, 64, e0, 0);
    STB(0, 128, e0, 0); STB(0, 192, e0, 0);
    STA(0, 0, 0); STA(0, 128, 0);
    STA(0, 64, 0); STA(0, 192, 0);
  }

  f32x16 acc[4][2];
#pragma unroll
  for (int mi = 0; mi < 4; ++mi)
#pragma unroll
    for (int ni = 0; ni < 2; ++ni)
#pragma unroll
      for (int r = 0; r < 16; ++r) acc[mi][ni][r] = 0.f;

  asm volatile("s_waitcnt vmcnt(2) lgkmcnt(0)" ::: "memory");
  SB; __builtin_amdgcn_s_barrier(); SB;

  bf16x8 bfr[2][4], afr[2][4];

#define TILE_BODY(T, BUF)                                                      \
  {                                                                            \
    const int t_ = (T);                                                        \
    const bool hasNext = (t_ + 1) < NT;                                        \
    const int kcN = ((t_ + 1) & 15) * 64;                                      \
    const size_t eoffN =                                                       \
        (size_t)(kh * 8 + ((t_ + 1) >> 4)) * (size_t)(DIN * DOUT);             \
    if ((t_ & 15) == 0 && t_ > 0) { /* expert boundary rescale */              \
      const int e = kh * 8 + (t_ >> 4);                                        \
      _Pragma("unroll") for (int mi = 0; mi < 4; ++mi)                         \
      _Pragma("unroll") for (int r = 0; r < 16; ++r) {                         \
        const int row = wm * 128 + mi * 32 + (r & 3) + 8 * (r >> 2) + 4 * lh;  \
        const float ratio = gs[row][e - 1] *                                   \
            __builtin_amdgcn_rcpf(fmaxf(gs[row][e], 1e-30f));                  \
        acc[mi][0][r] *= ratio; acc[mi][1][r] *= ratio;                        \
      }                                                                        \
    }                                                                          \
    /* stage t+1: B all + A h0 (6 chunks) */                                   \
    if (hasNext) {                                                             \
      STB(BUF ^ 1, 0, eoffN, kcN); STB(BUF ^ 1, 64, eoffN, kcN);               \
      STB(BUF ^ 1, 128, eoffN, kcN); STB(BUF ^ 1, 192, eoffN, kcN);            \
      STA(BUF ^ 1, 0, kcN); STA(BUF ^ 1, 128, kcN);                            \
    }                                                                          \
    /* first half: mi0,1 over all ks */                                        \
    RD_B(BUF); RD_A(0, 0, BUF); RD_A(1, 1, BUF);                               \
    __builtin_amdgcn_s_setprio(1); MFMA8(0, 0); MFMA8(1, 1);                   \
    __builtin_amdgcn_s_setprio(0);                                             \
    if (hasNext) { asm volatile("s_waitcnt vmcnt(6)" ::: "memory"); }          \
    else         { asm volatile("s_waitcnt vmcnt(0)" ::: "memory"); }          \
    SB;                                                                        \
    if (hasNext) { STA(BUF ^ 1, 64, kcN); STA(BUF ^ 1, 192, kcN); }            \
    /* second half: mi2,3 */                                                   \
    RD_A(2, 0, BUF); RD_A(3, 1, BUF);                                          \
    __builtin_amdgcn_s_setprio(1); MFMA8(2, 0); MFMA8(3, 1);                   \
    __builtin_amdgcn_s_setprio(0);                                             \
    if (hasNext) {                                                             \
      asm volatile("s_waitcnt vmcnt(2)" ::: "memory");                         \
      SB; __builtin_amdgcn_s_barrier(); SB;                                    \
    }                                                                          \
  }

  for (int tt = 0; tt < NT; tt += 2) {
    TILE_BODY(tt, 0);
    TILE_BODY(tt + 1, 1);
  }

  // epilogue: out = acc*g[eL] + sum_e g[e]*be[e,col]
  const int eL = kh * 8 + 7;
  float bv[8][2];
#pragma unroll
  for (int e8 = 0; e8 < 8; ++e8)
#pragma unroll
    for (int ni = 0; ni < 2; ++ni)
      bv[e8][ni] = be[(kh * 8 + e8) * DOUT + bcol + wn * 64 + ni * 32 + l31];
#pragma unroll
  for (int mi = 0; mi < 4; ++mi)
#pragma unroll
    for (int r = 0; r < 16; ++r) {
      const int row = wm * 128 + mi * 32 + (r & 3) + 8 * (r >> 2) + 4 * lh;
      const float gf = gs[row][eL];
      float b0 = 0.f, b1 = 0.f;
#pragma unroll
      for (int e8 = 0; e8 < 8; ++e8) {
        const float ge = gs[row][kh * 8 + e8];
        b0 = fmaf(ge, bv[e8][0], b0);
        b1 = fmaf(ge, bv[e8][1], b1);
      }
      float* const orp =
          outp + (size_t)(brow + row) * DOUT + bcol + wn * 64 + l31;
      orp[0]  = fmaf(acc[mi][0][r], gf, b0);
      orp[32] = fmaf(acc[mi][1][r], gf, b1);
    }
#undef TILE_BODY
#undef MFMA8
#undef RD_A
#undef RD_B
#undef STA
#undef STB
}

// ---------------- Kernel 4: combine out += p1 --------------------------------
__global__ __launch_bounds__(256) void combine_kernel(
    float* __restrict__ out, const float* __restrict__ p1) {
  const size_t i = (size_t)blockIdx.x * 256 + threadIdx.x;  // f32x4 index
  f32x4 a = ((const f32x4*)out)[i];
  const f32x4 b = ((const f32x4*)p1)[i];
#pragma unroll
  for (int q = 0; q < 4; ++q) a[q] += b[q];
  ((f32x4*)out)[i] = a;
}

// ---------------------------------------------------------------------------
extern "C" void kernel_launch(void* const* d_in, const int* in_sizes, int n_in,
                              void* d_out, int out_size, void* d_ws, size_t ws_size,
                              hipStream_t stream) {
  const float* x  = (const float*)d_in[0];
  const float* Wg = (const float*)d_in[1];
  const float* bg = (const float*)d_in[2];
  const float* We = (const float*)d_in[3];
  const float* be = (const float*)d_in[4];
  float* out = (float*)d_out;

  // ws: xbf 16MB | WeT 32MB | g 512KB | p1 32MB  (total 80.5MB)
  char* ws = (char*)d_ws;
  unsigned short* xbf = (unsigned short*)ws;
  unsigned short* WeT = (unsigned short*)(ws + (size_t)NB * DIN * 2);
  float* g = (float*)(ws + (size_t)NB * DIN * 2 + (size_t)NE * DIN * DOUT * 2);
  float* p1 = (float*)(ws + (size_t)NB * DIN * 2 + (size_t)NE * DIN * DOUT * 2 +
                       (size_t)NB * NE * 4);

  gate_cast_kernel<<<dim3(NB / 4), 256, 0, stream>>>(x, Wg, bg, g, xbf);
  we_transpose_kernel<<<dim3(DOUT / 64, DIN / 64, NE), 256, 0, stream>>>(We, WeT);
  moe_gemm_kernel<<<dim3(256), 512, 0, stream>>>(xbf, WeT, g, be, out, p1);
  combine_kernel<<<dim3(NB * DOUT / 4 / 256), 256, 0, stream>>>(out, p1);
}

// Round 8
// 339.628 us; speedup vs baseline: 1.0871x; 1.0871x over previous
//
#include <hip/hip_runtime.h>
#include <hip/hip_bf16.h>

// Problem: B=8192, D_IN=1024, D_OUT=1024, E=16
#define NB 8192
#define DIN 1024
#define DOUT 1024
#define NE 16

// GEMM tile geometry: split-K=2 (8 experts per block), BM=BN=256, BK=64
#define BM 256
#define BN 256
#define BK 64
#define NT 128  // (8 experts * 1024) / 64

typedef __attribute__((ext_vector_type(8))) short bf16x8;
typedef __attribute__((ext_vector_type(4))) short short4_t;
typedef __attribute__((ext_vector_type(4))) float f32x4;

__device__ __forceinline__ unsigned short f32_to_bf16(float f) {
  unsigned int u = __float_as_uint(f);
  u += 0x7FFFu + ((u >> 16) & 1u);  // RNE
  return (unsigned short)(u >> 16);
}

__device__ __forceinline__ void gl_lds16(const void* gp, void* lp) {
  __builtin_amdgcn_global_load_lds(
      (const __attribute__((address_space(1))) void*)gp,
      (__attribute__((address_space(3))) void*)lp, 16, 0, 0);
}

#define SB __builtin_amdgcn_sched_barrier(0)

// ---------------- Kernel 1: gate softmax (f32) + x -> bf16 cast --------------
__global__ __launch_bounds__(256) void gate_cast_kernel(
    const float* __restrict__ x, const float* __restrict__ Wg,
    const float* __restrict__ bg, float* __restrict__ gout,
    unsigned short* __restrict__ xbf) {
  const int lane = threadIdx.x & 63;
  const int wid = threadIdx.x >> 6;
  const int row = blockIdx.x * 4 + wid;

  const f32x4* xr = (const f32x4*)(x + (size_t)row * DIN);
  f32x4 xv[4];
#pragma unroll
  for (int j = 0; j < 4; ++j) xv[j] = xr[j * 64 + lane];

  float acc[NE];
#pragma unroll
  for (int e = 0; e < NE; ++e) acc[e] = 0.f;

#pragma unroll
  for (int j = 0; j < 4; ++j) {
#pragma unroll
    for (int t = 0; t < 4; ++t) {
      const int i = j * 256 + lane * 4 + t;
      const f32x4* wrow = (const f32x4*)(Wg + (size_t)i * NE);
      const f32x4 w0 = wrow[0], w1 = wrow[1], w2 = wrow[2], w3 = wrow[3];
      const float xx = xv[j][t];
#pragma unroll
      for (int q = 0; q < 4; ++q) {
        acc[q]      = fmaf(xx, w0[q], acc[q]);
        acc[4 + q]  = fmaf(xx, w1[q], acc[4 + q]);
        acc[8 + q]  = fmaf(xx, w2[q], acc[8 + q]);
        acc[12 + q] = fmaf(xx, w3[q], acc[12 + q]);
      }
    }
  }
#pragma unroll
  for (int off = 32; off >= 1; off >>= 1) {
#pragma unroll
    for (int e = 0; e < NE; ++e) acc[e] += __shfl_xor(acc[e], off, 64);
  }
#pragma unroll
  for (int e = 0; e < NE; ++e) acc[e] += bg[e];
  float mx = acc[0];
#pragma unroll
  for (int e = 1; e < NE; ++e) mx = fmaxf(mx, acc[e]);
  float p[NE];
  float s = 0.f;
#pragma unroll
  for (int e = 0; e < NE; ++e) { p[e] = expf(acc[e] - mx); s += p[e]; }
  const float inv = 1.f / s;
  if (lane == 0) {
#pragma unroll
    for (int e = 0; e < NE; ++e) gout[(size_t)row * NE + e] = p[e] * inv;
  }
#pragma unroll
  for (int j = 0; j < 4; ++j) {
    short4_t o;
#pragma unroll
    for (int t = 0; t < 4; ++t) o[t] = (short)f32_to_bf16(xv[j][t]);
    *(short4_t*)(xbf + (size_t)row * DIN + j * 256 + lane * 4) = o;
  }
}

// ------------- Kernel 2: We[e,i,o] f32 -> WeT[e,o,i] bf16 (transpose) --------
__global__ __launch_bounds__(256) void we_transpose_kernel(
    const float* __restrict__ We, unsigned short* __restrict__ WeT) {
  __shared__ float tile[64][65];
  const int e = blockIdx.z, it = blockIdx.y, ot = blockIdx.x;
  const int tr = threadIdx.x >> 4;
  const int tc = (threadIdx.x & 15) * 4;
  const float* src = We + (((size_t)e * DIN + it * 64) * DOUT) + ot * 64;
#pragma unroll
  for (int rr = 0; rr < 64; rr += 16) {
    const f32x4 v = *(const f32x4*)(src + (size_t)(rr + tr) * DOUT + tc);
#pragma unroll
    for (int t = 0; t < 4; ++t) tile[rr + tr][tc + t] = v[t];
  }
  __syncthreads();
  unsigned short* dst = WeT + (((size_t)e * DOUT + ot * 64) * DIN) + it * 64;
#pragma unroll
  for (int rr = 0; rr < 64; rr += 16) {
    short4_t o;
#pragma unroll
    for (int t = 0; t < 4; ++t) o[t] = (short)f32_to_bf16(tile[tc + t][rr + tr]);
    *(short4_t*)(dst + (size_t)(rr + tr) * DIN + tc) = o;
  }
}

// ------------- Kernel 3: split-K MoE GEMM, 4 phases, 5 barriers/tile ---------
// 8 waves 2Mx4N, per-wave 128x64. P0 mi0-3/ks0, P1 mi0-3/ks1, P2 mi4-7/ks0,
// P3 mi4-7/ks1. One pre-MFMA barrier per phase + one boundary barrier.
// Scheduling pins are MINIMAL: exactly one sched_barrier(0) after each
// s_barrier (prevents hoisting buffer reads above the sync). The compiler is
// otherwise free to interleave ds_reads/address VALU with MFMA (m141 lesson).
// Stage for t+1: P0 Bh0, P1 Bh1, P2 Ah0, P3 Ah1. Waits: end-P1 vmcnt(4)
// (drains this tile's Ah1 before P2 reads), boundary vmcnt(2).
__global__ __launch_bounds__(512, 2) void moe_gemm_kernel(
    const unsigned short* __restrict__ xbf,   // [8192][1024] bf16
    const unsigned short* __restrict__ WeT,   // [16][1024 o][1024 i] bf16
    const float* __restrict__ g,              // [8192][16]
    const float* __restrict__ be,             // [16][1024]
    float* __restrict__ out0,                 // kh=0 -> d_out
    float* __restrict__ out1) {               // kh=1 -> partial ws
  __shared__ __align__(16) unsigned short As[2][BM * BK];  // 2x32 KiB
  __shared__ __align__(16) unsigned short Bs[2][BN * BK];  // 2x32 KiB
  __shared__ float gs[BM][NE];                             // 16 KiB

  const int tid = threadIdx.x;
  const int lane = tid & 63, wid = tid >> 6;
  const int wm = wid >> 2, wn = wid & 3;
  const int l15 = lane & 15, l4 = lane >> 4;

  const int bid = blockIdx.x;
  const int xcd = bid & 7, jj_ = bid >> 3;
  const int kh = xcd >> 2;
  const int brow = ((xcd & 3) * 8 + (jj_ >> 2)) * BM;
  const int bcol = (jj_ & 3) * BN;
  float* const outp = kh ? out1 : out0;

  // precomputed per-thread LDS read bases; swizzle depends only on (l15,l4,ks)
  const int swz0 = (l4 * 16) ^ ((l15 & 7) << 4);
  const int swz1 = (64 + l4 * 16) ^ ((l15 & 7) << 4);
  const char* const ldsA0 = (const char*)&As[0][0] + (wm * 128 + l15) * 128 + swz0;
  const char* const ldsA1 = (const char*)&As[0][0] + (wm * 128 + l15) * 128 + swz1;
  const char* const ldsB0 = (const char*)&Bs[0][0] + (wn * 64 + l15) * 128 + swz0;
  const char* const ldsB1 = (const char*)&Bs[0][0] + (wn * 64 + l15) * 128 + swz1;

  // staging precompute (T2 both-sides: linear LDS dst, inverse-swz global src)
  const int srow = tid >> 3;
  const int lk = (((tid & 7) * 16) ^ ((srow & 7) << 4)) >> 1;
  const unsigned short* const aBase = xbf + (size_t)(brow + srow) * DIN + lk;
  const unsigned short* const bBase = WeT + (size_t)(bcol + srow) * DIN + lk;
  char* const ldsStA = (char*)&As[0][0] + wid * 1024;  // wave-uniform
  char* const ldsStB = (char*)&Bs[0][0] + wid * 1024;

#define STA(BUF, CR, KC) \
  gl_lds16(aBase + (size_t)(CR) * DIN + (KC), ldsStA + (BUF) * 32768 + (CR) * 128)
#define STB(BUF, CR, EOFF, KC) \
  gl_lds16(bBase + (EOFF) + (size_t)(CR) * DIN + (KC), \
           ldsStB + (BUF) * 32768 + (CR) * 128)
#define RD_B(KS, BUF)                                             \
  _Pragma("unroll") for (int ni = 0; ni < 4; ++ni)                \
      bfr[ni][KS] = *(const bf16x8*)(((KS) ? ldsB1 : ldsB0) +     \
                                     ni * 2048 + (BUF) * 32768);
#define RD_A(KS, MI0, BUF)                                        \
  _Pragma("unroll") for (int d = 0; d < 4; ++d)                   \
      af[d] = *(const bf16x8*)(((KS) ? ldsA1 : ldsA0) +           \
                               ((MI0) + d) * 2048 + (BUF) * 32768);
#define MFMA_P(MI0, KS)                                            \
  _Pragma("unroll") for (int d = 0; d < 4; ++d)                    \
  _Pragma("unroll") for (int ni = 0; ni < 4; ++ni)                 \
      acc[(MI0) + d][ni] = __builtin_amdgcn_mfma_f32_16x16x32_bf16(\
          af[d], bfr[ni][KS], acc[(MI0) + d][ni], 0, 0, 0);

  {  // gate tile -> LDS
    const f32x4* gsrc = (const f32x4*)(g + (size_t)brow * NE);
    f32x4* gdst = (f32x4*)&gs[0][0];
    gdst[tid] = gsrc[tid];
    gdst[tid + 512] = gsrc[tid + 512];
  }

  // prologue: stage tile 0, deadline order Bh0,Bh1,Ah0 then Ah1
  {
    const size_t e0 = (size_t)(kh * 8) * (size_t)(DIN * DOUT);
    STB(0, 0, e0, 0);  STB(0, 128, e0, 0);
    STB(0, 64, e0, 0); STB(0, 192, e0, 0);
    STA(0, 0, 0);      STA(0, 128, 0);
    STA(0, 64, 0);     STA(0, 192, 0);
  }

  f32x4 acc[8][4];
#pragma unroll
  for (int mi = 0; mi < 8; ++mi)
#pragma unroll
    for (int ni = 0; ni < 4; ++ni) acc[mi][ni] = (f32x4){0.f, 0.f, 0.f, 0.f};

  asm volatile("s_waitcnt vmcnt(2) lgkmcnt(0)" ::: "memory");
  __builtin_amdgcn_s_barrier(); SB;

  bf16x8 bfr[4][2], af[4];

#define TILE_BODY(T, BUF)                                                      \
  {                                                                            \
    const int t_ = (T);                                                        \
    const int kcN = ((t_ + 1) & 15) * 64;                                      \
    const size_t eoffN =                                                       \
        (size_t)(kh * 8 + ((t_ + 1) >> 4)) * (size_t)(DIN * DOUT);             \
    const bool hasNext = (t_ + 1) < NT;                                        \
    if ((t_ & 15) == 0 && t_ > 0) { /* expert boundary rescale */              \
      const int e = kh * 8 + (t_ >> 4);                                        \
      _Pragma("unroll") for (int mi = 0; mi < 8; ++mi) {                       \
        const int rb = wm * 128 + mi * 16 + l4 * 4;                            \
        _Pragma("unroll") for (int q = 0; q < 4; ++q) {                        \
          const float r = gs[rb + q][e - 1] *                                  \
                          __builtin_amdgcn_rcpf(fmaxf(gs[rb + q][e], 1e-30f)); \
          _Pragma("unroll") for (int ni = 0; ni < 4; ++ni)                     \
              acc[mi][ni][q] *= r;                                             \
        }                                                                      \
      }                                                                        \
    }                                                                          \
    /* ===== P0: mi0-3, ks0 ===== */                                           \
    RD_B(0, BUF); RD_A(0, 0, BUF);                                             \
    if (hasNext) { STB(BUF ^ 1, 0, eoffN, kcN); STB(BUF ^ 1, 128, eoffN, kcN); } \
    __builtin_amdgcn_s_barrier(); SB;                                          \
    __builtin_amdgcn_s_setprio(1); MFMA_P(0, 0);                               \
    __builtin_amdgcn_s_setprio(0);                                             \
    /* ===== P1: mi0-3, ks1 ===== */                                           \
    RD_B(1, BUF); RD_A(1, 0, BUF);                                             \
    if (hasNext) { STB(BUF ^ 1, 64, eoffN, kcN); STB(BUF ^ 1, 192, eoffN, kcN); } \
    if (t_ == NT - 1) { asm volatile("s_waitcnt vmcnt(0)" ::: "memory"); }     \
    else { asm volatile("s_waitcnt vmcnt(4)" ::: "memory"); }                  \
    __builtin_amdgcn_s_barrier(); SB;                                          \
    __builtin_amdgcn_s_setprio(1); MFMA_P(0, 1);                               \
    __builtin_amdgcn_s_setprio(0);                                             \
    /* ===== P2: mi4-7, ks0 ===== */                                           \
    RD_A(0, 4, BUF);                                                           \
    if (hasNext) { STA(BUF ^ 1, 0, kcN); STA(BUF ^ 1, 128, kcN); }             \
    __builtin_amdgcn_s_barrier(); SB;                                          \
    __builtin_amdgcn_s_setprio(1); MFMA_P(4, 0);                               \
    __builtin_amdgcn_s_setprio(0);                                             \
    /* ===== P3: mi4-7, ks1 ===== */                                           \
    RD_A(1, 4, BUF);                                                           \
    if (hasNext) { STA(BUF ^ 1, 64, kcN); STA(BUF ^ 1, 192, kcN); }            \
    __builtin_amdgcn_s_barrier(); SB;                                          \
    __builtin_amdgcn_s_setprio(1); MFMA_P(4, 1);                               \
    __builtin_amdgcn_s_setprio(0);                                             \
    if ((t_ & 15) == 15) { /* bias for expert e */                             \
      const int e = kh * 8 + (t_ >> 4);                                        \
      _Pragma("unroll") for (int ni = 0; ni < 4; ++ni) {                       \
        const float bv = be[e * DOUT + bcol + wn * 64 + ni * 16 + l15];        \
        _Pragma("unroll") for (int mi = 0; mi < 8; ++mi)                       \
          _Pragma("unroll") for (int q = 0; q < 4; ++q)                        \
              acc[mi][ni][q] += bv;                                            \
      }                                                                        \
    }                                                                          \
    if (t_ < NT - 1) { asm volatile("s_waitcnt vmcnt(2)" ::: "memory"); }      \
    __builtin_amdgcn_s_barrier(); SB;                                          \
  }

  for (int tt = 0; tt < NT; tt += 2) {
    TILE_BODY(tt, 0);
    TILE_BODY(tt + 1, 1);
  }

  // epilogue: scale by this half's last gate, store
  const int eL = kh * 8 + 7;
#pragma unroll
  for (int mi = 0; mi < 8; ++mi) {
    const int rb = wm * 128 + mi * 16 + l4 * 4;
#pragma unroll
    for (int q = 0; q < 4; ++q) {
      const float gf = gs[rb + q][eL];
      const size_t orow = (size_t)brow + rb + q;
#pragma unroll
      for (int ni = 0; ni < 4; ++ni)
        outp[orow * DOUT + bcol + wn * 64 + ni * 16 + l15] =
            acc[mi][ni][q] * gf;
    }
  }
#undef TILE_BODY
#undef MFMA_P
#undef RD_A
#undef RD_B
#undef STA
#undef STB
}

// ---------------- Kernel 4: combine out += p1 --------------------------------
__global__ __launch_bounds__(256) void combine_kernel(
    float* __restrict__ out, const float* __restrict__ p1) {
  const size_t i = (size_t)blockIdx.x * 256 + threadIdx.x;  // f32x4 index
  f32x4 a = ((const f32x4*)out)[i];
  const f32x4 b = ((const f32x4*)p1)[i];
#pragma unroll
  for (int q = 0; q < 4; ++q) a[q] += b[q];
  ((f32x4*)out)[i] = a;
}

// ---------------------------------------------------------------------------
extern "C" void kernel_launch(void* const* d_in, const int* in_sizes, int n_in,
                              void* d_out, int out_size, void* d_ws, size_t ws_size,
                              hipStream_t stream) {
  const float* x  = (const float*)d_in[0];
  const float* Wg = (const float*)d_in[1];
  const float* bg = (const float*)d_in[2];
  const float* We = (const float*)d_in[3];
  const float* be = (const float*)d_in[4];
  float* out = (float*)d_out;

  // ws: xbf 16MB | WeT 32MB | g 512KB | p1 32MB  (total 80.5MB)
  char* ws = (char*)d_ws;
  unsigned short* xbf = (unsigned short*)ws;
  unsigned short* WeT = (unsigned short*)(ws + (size_t)NB * DIN * 2);
  float* g = (float*)(ws + (size_t)NB * DIN * 2 + (size_t)NE * DIN * DOUT * 2);
  float* p1 = (float*)(ws + (size_t)NB * DIN * 2 + (size_t)NE * DIN * DOUT * 2 +
                       (size_t)NB * NE * 4);

  gate_cast_kernel<<<dim3(NB / 4), 256, 0, stream>>>(x, Wg, bg, g, xbf);
  we_transpose_kernel<<<dim3(DOUT / 64, DIN / 64, NE), 256, 0, stream>>>(We, WeT);
  moe_gemm_kernel<<<dim3(256), 512, 0, stream>>>(xbf, WeT, g, be, out, p1);
  combine_kernel<<<dim3(NB * DOUT / 4 / 256), 256, 0, stream>>>(out, p1);
}